// Round 10
// baseline (276.198 us; speedup 1.0000x reference)
//
#include <hip/hip_runtime.h>
#include <hip/hip_bf16.h>
#include <cstdint>

#define B_ 256
#define P_ 196
#define D_ 512
#define A_ 512

#define OUT_CHAT  0
#define OUT_ALPHA (B_*D_)            // 131072
#define OUT_BETA  (B_*D_ + B_*P_)    // 181248

typedef unsigned short ushort_t;
typedef uint32_t u32;
typedef uint64_t u64;
typedef __attribute__((ext_vector_type(8))) __bf16 bf16x8;
typedef __attribute__((ext_vector_type(4))) float f32x4;

__device__ __forceinline__ ushort_t f2bf(float f) {
    union { float f; u32 i; } v; v.f = f;
    u32 r = (v.i + 0x7fffu + ((v.i >> 16) & 1u)) >> 16;
    return (ushort_t)r;
}
__device__ __forceinline__ float bfbits2f(u32 lo16) {
    union { u32 i; float f; } v; v.i = lo16 << 16; return v.f;
}
// HW packed f32->bf16 (v_cvt_pk_bf16_f32 on gfx950)
__device__ __forceinline__ u32 cvt2bf(float x, float y) {
    union { __hip_bfloat162 h; u32 u; } v;
    v.h = __float22bfloat162_rn(make_float2(x, y));
    return v.u;
}
__device__ __forceinline__ float tanh_fast(float x) {
    float e = __expf(2.0f * x);
    return 1.0f - 2.0f / (e + 1.0f);
}
// async 16B global->LDS (global_load_lds_dwordx4); LDS dest must be
// wave-uniform base + lane*16 — our staging maps guarantee that.
__device__ __forceinline__ void async_load16(const ushort_t* g, ushort_t* l) {
    __builtin_amdgcn_global_load_lds(
        (const __attribute__((address_space(1))) unsigned int*)g,
        (__attribute__((address_space(3))) unsigned int*)l, 16, 0, 0);
}

// ---- k_prep: [0,12544) Ebf=bf16(E); [12544,12672) dh/st cvt;
//              [12672,13440) transposes WT[a][d]=bf16(W[d][a]) ----
__global__ __launch_bounds__(256) void k_prep(
    const float* __restrict__ E, const float* __restrict__ dh,
    const float* __restrict__ st,
    const float* __restrict__ Wv, const float* __restrict__ Wh,
    const float* __restrict__ Ws,
    ushort_t* __restrict__ Ebf, ushort_t* __restrict__ dhbf,
    ushort_t* __restrict__ stbf,
    ushort_t* __restrict__ WvT, ushort_t* __restrict__ WhT,
    ushort_t* __restrict__ WsT)
{
    __shared__ ushort_t tile[32][33];
    int bx = blockIdx.x;
    if (bx < 12544) {
        size_t i0 = (size_t)bx * 512 + threadIdx.x;
        const float4* src = (const float4*)E;
        u64* dst = (u64*)Ebf;
        float4 v0 = src[i0];
        float4 v1 = src[i0 + 256];
        dst[i0]       = (u64)cvt2bf(v0.x, v0.y) | ((u64)cvt2bf(v0.z, v0.w) << 32);
        dst[i0 + 256] = (u64)cvt2bf(v1.x, v1.y) | ((u64)cvt2bf(v1.z, v1.w) << 32);
    } else if (bx < 12672) {
        int gid = (bx - 12544) * 256 + threadIdx.x;   // 0..32767
        float4 dv = ((const float4*)dh)[gid];
        float4 sv = ((const float4*)st)[gid];
        ((u64*)dhbf)[gid] = (u64)cvt2bf(dv.x, dv.y) | ((u64)cvt2bf(dv.z, dv.w) << 32);
        ((u64*)stbf)[gid] = (u64)cvt2bf(sv.x, sv.y) | ((u64)cvt2bf(sv.z, sv.w) << 32);
    } else {
        int idx = bx - 12672;            // 0..767
        int z   = idx >> 8;              // which matrix
        int rem = idx & 255;
        int tby = rem >> 4, tbx = rem & 15;
        const float* W  = (z == 0) ? Wv  : (z == 1) ? Wh  : Ws;
        ushort_t*    WT = (z == 0) ? WvT : (z == 1) ? WhT : WsT;
        int t = threadIdx.x, r = t >> 5, c = t & 31;
#pragma unroll
        for (int i = 0; i < 4; ++i) {
            int row = r + 8 * i;
            tile[row][c] = f2bf(W[(size_t)(tby * 32 + row) * A_ + tbx * 32 + c]);
        }
        __syncthreads();
#pragma unroll
        for (int i = 0; i < 4; ++i) {
            int row = r + 8 * i;
            WT[(size_t)(tbx * 32 + row) * D_ + tby * 32 + c] = tile[c][row];
        }
    }
}

#define PADK 72   // used by k1 only

// ---- k1_mfma: hidden = dh@Wh+bh (z=0) and s = st@Ws+bs (z=1) ----
__global__ __launch_bounds__(256) void k1_mfma(
    const ushort_t* __restrict__ dhbf, const ushort_t* __restrict__ stbf,
    const ushort_t* __restrict__ WhT,  const ushort_t* __restrict__ WsT,
    const float* __restrict__ bh, const float* __restrict__ bs,
    float* __restrict__ hidden_ws, float* __restrict__ s_ws)
{
    __shared__ ushort_t As[128 * PADK];
    __shared__ ushort_t Bs[128 * PADK];

    int mat = blockIdx.z;
    const ushort_t* Abf = mat ? stbf : dhbf;
    const ushort_t* WT  = mat ? WsT  : WhT;
    const float*    bia = mat ? bs   : bh;
    float*          outp = mat ? s_ws : hidden_ws;

    int tid = threadIdx.x;
    int m0 = blockIdx.y * 128;
    int n0 = blockIdx.x * 128;

    int lane = tid & 63, w = tid >> 6;
    int wm = w & 1, wn = w >> 1;
    int col = lane & 15, q = lane >> 4;

    f32x4 acc[4][4];
#pragma unroll
    for (int tm = 0; tm < 4; ++tm)
#pragma unroll
        for (int tn = 0; tn < 4; ++tn)
            acc[tm][tn] = (f32x4){0.f, 0.f, 0.f, 0.f};

    const ushort_t* arow = As + (wm * 64 + col) * PADK + q * 8;
    const ushort_t* brow = Bs + (wn * 64 + col) * PADK + q * 8;

    int sr = tid >> 3, sc = tid & 7;
    for (int kt = 0; kt < D_ / 64; ++kt) {
#pragma unroll
        for (int i = 0; i < 4; ++i) {
            int row = sr + i * 32;
            *(uint4*)(As + row * PADK + sc * 8) =
                *(const uint4*)(Abf + (size_t)(m0 + row) * D_ + kt * 64 + sc * 8);
            *(uint4*)(Bs + row * PADK + sc * 8) =
                *(const uint4*)(WT + (size_t)(n0 + row) * D_ + kt * 64 + sc * 8);
        }
        __syncthreads();
#pragma unroll
        for (int ks = 0; ks < 2; ++ks) {
            bf16x8 afr[4];
#pragma unroll
            for (int tm = 0; tm < 4; ++tm)
                afr[tm] = *(const bf16x8*)(arow + tm * 16 * PADK + ks * 32);
#pragma unroll
            for (int tn = 0; tn < 4; ++tn) {
                bf16x8 bfr = *(const bf16x8*)(brow + tn * 16 * PADK + ks * 32);
#pragma unroll
                for (int tm = 0; tm < 4; ++tm)
                    acc[tm][tn] = __builtin_amdgcn_mfma_f32_16x16x32_bf16(
                        afr[tm], bfr, acc[tm][tn], 0, 0, 0);
            }
        }
        __syncthreads();
    }

#pragma unroll
    for (int tm = 0; tm < 4; ++tm)
#pragma unroll
        for (int r = 0; r < 4; ++r) {
            int b = m0 + wm * 64 + tm * 16 + q * 4 + r;
#pragma unroll
            for (int tn = 0; tn < 4; ++tn) {
                int n = n0 + wn * 64 + tn * 16 + col;
                outp[(size_t)b * A_ + n] = acc[tm][tn][r] + bia[n];
            }
        }
}

// ---- K2: z partials, ping-pong double-buffered async-LDS GEMM ----
// BM=128, BN=256, BK=32, 16 K-iterations. Loads for kt+1 issued into the
// other buffer BEFORE computing kt -> loads land during compute, the single
// per-kt barrier drains an already-complete queue. LDS 52 KB -> 3 blocks/CU.
#define BM 128
#define BN 256
#define BKp 32
__global__ __launch_bounds__(256, 3) void k2_z_bf(
    const ushort_t* __restrict__ Ebf, const ushort_t* __restrict__ WvT,
    const float* __restrict__ hidden_ws, const float* __restrict__ bv,
    const float* __restrict__ Wav, float* __restrict__ z2_ws)
{
    __shared__ ushort_t As[2][BM * BKp];   // 2 x 8 KB
    __shared__ ushort_t Bs[2][BN * BKp];   // 2 x 16 KB
    __shared__ float hv_s[2][BN];
    __shared__ float wav_s[BN];
    __shared__ float zpart[2][BM];

    int tid = threadIdx.x;
    int m0  = blockIdx.x * BM;
    int n0  = blockIdx.y * BN;
    int b0  = m0 / P_;
    int b1  = (m0 + BM - 1) / P_;

    // staging geometry: thread handles 16B chunk (row = tid>>2 [+64/pass],
    // chunk pos = tid&3); fetch global chunk (pos ^ (row&3)) — row&3
    // invariant under +64 so one swizzle per thread.
    int srow = tid >> 2, spos = tid & 3;
    int gch  = spos ^ (srow & 3);
    const ushort_t* agb = Ebf + (size_t)(m0 + srow) * D_ + gch * 8;
    const ushort_t* bgb = WvT + (size_t)(n0 + srow) * D_ + gch * 8;

    int lane = tid & 63, w = tid >> 6;
    int wm = w & 1, wn = w >> 1;
    int col = lane & 15, q = lane >> 4;
    int fx = col & 3;   // frag-read swizzle: row&3 == col&3 for all frag rows

    f32x4 acc[4][8];
#pragma unroll
    for (int tm = 0; tm < 4; ++tm)
#pragma unroll
        for (int tn = 0; tn < 8; ++tn)
            acc[tm][tn] = (f32x4){0.f, 0.f, 0.f, 0.f};

    // prologue: stage kt=0 into buffer 0; stage hv/wav
    {
#pragma unroll
        for (int i = 0; i < 2; ++i)
            async_load16(agb + (size_t)i * 64 * D_, &As[0][tid * 8 + i * 2048]);
#pragma unroll
        for (int i = 0; i < 4; ++i)
            async_load16(bgb + (size_t)i * 64 * D_, &Bs[0][tid * 8 + i * 2048]);
        int a = n0 + tid;
        float bva = bv[a];
        hv_s[0][tid] = hidden_ws[(size_t)b0 * A_ + a] + bva;
        hv_s[1][tid] = hidden_ws[(size_t)b1 * A_ + a] + bva;
        wav_s[tid]   = Wav[a];
    }
    __syncthreads();

#pragma unroll
    for (int kt = 0; kt < 16; ++kt) {
        int cb = kt & 1;
        if (kt < 15) {   // issue next tile's loads into the other buffer
            int nb = cb ^ 1;
#pragma unroll
            for (int i = 0; i < 2; ++i)
                async_load16(agb + (size_t)i * 64 * D_ + (kt + 1) * BKp,
                             &As[nb][tid * 8 + i * 2048]);
#pragma unroll
            for (int i = 0; i < 4; ++i)
                async_load16(bgb + (size_t)i * 64 * D_ + (kt + 1) * BKp,
                             &Bs[nb][tid * 8 + i * 2048]);
        }
        // compute kt on current buffer (loads for kt+1 in flight)
        bf16x8 afr[4];
#pragma unroll
        for (int tm = 0; tm < 4; ++tm)
            afr[tm] = *(const bf16x8*)(&As[cb][(wm * 64 + tm * 16 + col) * BKp
                                              + ((q ^ fx) * 8)]);
#pragma unroll
        for (int tn = 0; tn < 8; ++tn) {
            bf16x8 bfr = *(const bf16x8*)(&Bs[cb][(wn * 128 + tn * 16 + col) * BKp
                                                  + ((q ^ fx) * 8)]);
#pragma unroll
            for (int tm = 0; tm < 4; ++tm)
                acc[tm][tn] = __builtin_amdgcn_mfma_f32_16x16x32_bf16(
                    afr[tm], bfr, acc[tm][tn], 0, 0, 0);
        }
        __syncthreads();
    }

#pragma unroll
    for (int tm = 0; tm < 4; ++tm) {
#pragma unroll
        for (int r = 0; r < 4; ++r) {
            int row = wm * 64 + tm * 16 + q * 4 + r;
            int m   = m0 + row;
            int bsel = (m / P_) - b0;
            float zr = 0.f;
#pragma unroll
            for (int tn = 0; tn < 8; ++tn) {
                int nl = wn * 128 + tn * 16 + col;
                zr += wav_s[nl] * tanh_fast(acc[tm][tn][r] + hv_s[bsel][nl]);
            }
#pragma unroll
            for (int msk = 1; msk < 16; msk <<= 1)
                zr += __shfl_xor(zr, msk, 64);
            if (col == 0) zpart[wn][row] = zr;
        }
    }
    __syncthreads();
    if (tid < BM)
        z2_ws[(size_t)blockIdx.y * (B_ * P_) + m0 + tid] =
            zpart[0][tid] + zpart[1][tid];
}

// ---- K3: s_att; softmax(z+bav) -> alpha; extended -> beta ----
__global__ __launch_bounds__(256) void k3_softmax(
    const float* __restrict__ z2_ws, const float* __restrict__ hidden_ws,
    const float* __restrict__ s_ws, const float* __restrict__ Was,
    const float* __restrict__ bas, const float* __restrict__ bav,
    float* __restrict__ alpha_ws, float* __restrict__ beta_ws,
    float* __restrict__ out)
{
    __shared__ float red[4];
    __shared__ float bm_s, bl_s, sa_s;
    int b = blockIdx.x, t = threadIdx.x;

    {
        int a0 = t, a1 = t + 256;
        float part = Was[a0] * tanh_fast(s_ws[(size_t)b * A_ + a0] + hidden_ws[(size_t)b * A_ + a0])
                   + Was[a1] * tanh_fast(s_ws[(size_t)b * A_ + a1] + hidden_ws[(size_t)b * A_ + a1]);
#pragma unroll
        for (int o = 32; o >= 1; o >>= 1) part += __shfl_down(part, o, 64);
        if ((t & 63) == 0) red[t >> 6] = part;
        __syncthreads();
        if (t == 0) sa_s = red[0] + red[1] + red[2] + red[3] + bas[0];
        __syncthreads();
    }

    float zv = (t < P_) ? (z2_ws[(size_t)b * P_ + t]
                         + z2_ws[(size_t)(B_ * P_) + (size_t)b * P_ + t] + bav[0])
                        : -1e30f;

    float m = zv;
#pragma unroll
    for (int o = 32; o >= 1; o >>= 1) m = fmaxf(m, __shfl_xor(m, o, 64));
    if ((t & 63) == 0) red[t >> 6] = m;
    __syncthreads();
    if (t == 0) bm_s = fmaxf(fmaxf(red[0], red[1]), fmaxf(red[2], red[3]));
    __syncthreads();
    float m1 = bm_s;

    float e = (t < P_) ? __expf(zv - m1) : 0.f;
    float s = e;
#pragma unroll
    for (int o = 32; o >= 1; o >>= 1) s += __shfl_xor(s, o, 64);
    if ((t & 63) == 0) red[t >> 6] = s;
    __syncthreads();
    if (t == 0) bl_s = red[0] + red[1] + red[2] + red[3];
    __syncthreads();
    float l1 = bl_s;

    if (t < P_) {
        float alpha = e / l1;
        alpha_ws[(size_t)b * P_ + t] = alpha;
        out[OUT_ALPHA + (size_t)b * P_ + t] = alpha;
    }
    float sa = sa_s;
    float m2 = fmaxf(m1, sa);
    float l2 = __expf(m1 - m2) * l1 + __expf(sa - m2);
    float beta = __expf(sa - m2) / l2;
    if (t == 0) {
        beta_ws[b] = beta;
        out[OUT_BETA + b] = beta;
    }
}

// ---- K4: c_hat = beta*st + (1-beta) * (Ebf[b]^T alpha)  (fused, bf16 E) ----
__global__ __launch_bounds__(256) void k4_final(
    const ushort_t* __restrict__ Ebf, const float* __restrict__ st,
    const float* __restrict__ alpha_ws, const float* __restrict__ beta_ws,
    float* __restrict__ out)
{
    __shared__ float al[P_];
    int b = blockIdx.x, t = threadIdx.x;
    if (t < P_) al[t] = alpha_ws[(size_t)b * P_ + t];
    __syncthreads();
    // thread t covers d = 2t, 2t+1; one u32 (2 bf16) per p-row
    const u32* eb = (const u32*)(Ebf + (size_t)b * P_ * D_) + t;
    float a0 = 0.f, a1 = 0.f;
#pragma unroll 4
    for (int p = 0; p < P_; ++p) {
        u32 u = eb[(size_t)p * (D_ / 2)];
        float ap = al[p];
        a0 = fmaf(ap, bfbits2f(u & 0xffffu), a0);
        a1 = fmaf(ap, bfbits2f(u >> 16), a1);
    }
    float beta = beta_ws[b];
    float2 su = *(const float2*)(st + (size_t)b * D_ + 2 * t);
    float c0 = beta * su.x + (1.f - beta) * a0;
    float c1 = beta * su.y + (1.f - beta) * a1;
    *(float2*)(out + (size_t)b * D_ + 2 * t) = make_float2(c0, c1);
}

extern "C" void kernel_launch(void* const* d_in, const int* in_sizes, int n_in,
                              void* d_out, int out_size, void* d_ws, size_t ws_size,
                              hipStream_t stream)
{
    (void)in_sizes; (void)n_in; (void)out_size; (void)ws_size;
    const float* E   = (const float*)d_in[0];
    const float* dh  = (const float*)d_in[1];
    const float* st  = (const float*)d_in[2];
    const float* Wv  = (const float*)d_in[3];
    const float* bv  = (const float*)d_in[4];
    const float* Wh  = (const float*)d_in[5];
    const float* bh  = (const float*)d_in[6];
    const float* Ws  = (const float*)d_in[7];
    const float* bs  = (const float*)d_in[8];
    const float* Wav = (const float*)d_in[9];
    const float* bav = (const float*)d_in[10];
    const float* Was = (const float*)d_in[11];
    const float* bas = (const float*)d_in[12];
    float* out = (float*)d_out;

    char* ws = (char*)d_ws;
    ushort_t* WvT     = (ushort_t*)(ws);            //  524288
    ushort_t* WhT     = (ushort_t*)(ws + 524288);   //  524288
    ushort_t* WsT     = (ushort_t*)(ws + 1048576);  //  524288
    float*    alpha_w = (float*)(ws + 1572864);     //  200704
    float*    beta_w  = (float*)(ws + 1773568);     //    1024
    float*    z2_w    = (float*)(ws + 1774592);     //  401408 (2 x B x P)
    ushort_t* dhbf    = (ushort_t*)(ws + 2176000);  //  262144
    ushort_t* stbf    = (ushort_t*)(ws + 2438144);  //  262144
    float*    hidden_w= (float*)(ws + 2700288);     //  524288
    float*    s_w     = (float*)(ws + 3224576);     //  524288
    ushort_t* Ebf     = (ushort_t*)(ws + 3748864);  // 51380224 (total ~55.1 MB)

    k_prep<<<12544 + 128 + 768, 256, 0, stream>>>(E, dh, st, Wv, Wh, Ws,
                                                  Ebf, dhbf, stbf, WvT, WhT, WsT);
    k1_mfma<<<dim3(4, 2, 2), 256, 0, stream>>>(dhbf, stbf, WhT, WsT, bh, bs,
                                               hidden_w, s_w);
    k2_z_bf<<<dim3((B_ * P_) / BM, A_ / BN), 256, 0, stream>>>(
        Ebf, WvT, hidden_w, bv, Wav, z2_w);
    k3_softmax<<<256, 256, 0, stream>>>(z2_w, hidden_w, s_w, Was, bas, bav,
                                        alpha_w, beta_w, out);
    k4_final<<<256, 256, 0, stream>>>(Ebf, st, alpha_w, beta_w, out);
}